// Round 14
// baseline (47.168 us; speedup 1.0000x reference)
//
#include <hip/hip_runtime.h>
#include <math.h>
#include <stdint.h>

// ContrastiveLoss: N=8192, C=512, NC=100, MARGIN=1.0
// loss = (sum_{i!=j,same} d_ij + sum_{i!=j,diff} max(0, 1-sqrt(d_ij))^2) / (2*N*(N-1))
// d_ij = |xi|^2+|xj|^2-2 xi.xj (clamped at 0).
//
// Round 14: dispatch-rate probe. Same algebra/kernels as R13 but grid-stride
// persistence: prep 512 blocks x 16 rows (was 2048x4), filter 520 blocks x 4
// tiles (was 2080x1, LDS re-staged per tile). Block count 4898 -> 1802.
// If total drops ~proportionally, dispatch rate was the hidden cost.

static constexpr int   Nn  = 8192;
static constexpr int   Cc  = 512;
static constexpr float MRG = 1.0f;
static constexpr int   KF  = 32;          // filter features
static constexpr float FILT_THR = 2.0f;   // margin^2 + bf16-error slack

static constexpr int NBLKF   = Nn / 128;                  // 64
static constexpr int NPAIRSF = NBLKF * (NBLKF + 1) / 2;   // 2080
static constexpr int FILT_BLKS = 520;                     // x4 tiles each
static constexpr int NCLS    = 100;
static constexpr int NBINS   = NCLS * Cc;                 // 51200

static constexpr int NCHUNK  = 32;        // row chunks (256 rows each)
static constexpr int DG      = 32;        // dims per group
static constexpr int NDG     = Cc / DG;   // 16 dim groups

static constexpr int PREP_BLKS  = 512;             // 16 rows each
static constexpr int CLSUM_BLKS = NCHUNK * NDG;    // 512
static constexpr int MSQ_BLKS   = 256;             // 200 bins each
static constexpr int F2_BLKS    = FILT_BLKS + MSQ_BLKS + 1;   // 777

static constexpr float SCALE_M  = 65536.0f;     // Q16 (int32 bins)
static constexpr float SCALE_S2 = 1048576.0f;   // Q20 (int64)

// ---- fp32 fallback config (small-ws path) ----
static constexpr int BM1     = 64;
static constexpr int BK1     = 32;
static constexpr int NBLK1   = Nn / BM1;
static constexpr int NPAIRS1 = NBLK1 * (NBLK1 + 1) / 2;
static constexpr int LSTR    = 68;

typedef __attribute__((ext_vector_type(8))) short short8v;
typedef __attribute__((ext_vector_type(4))) float f32x4;

static __device__ inline unsigned short f2bf(float x) {
    unsigned u = __float_as_uint(x);
    unsigned rnd = 0x7FFFu + ((u >> 16) & 1u);
    return (unsigned short)((u + rnd) >> 16);
}

// ---------------------------------------------------------------- fused1: prep || clsum
__global__ __launch_bounds__(256) void fused1_kernel(const float* __restrict__ f,
                                                     const int* __restrict__ tgt,
                                                     unsigned short* __restrict__ fb32,
                                                     float* __restrict__ sq32,
                                                     float* __restrict__ sqAll,
                                                     int* __restrict__ partials) {
    __shared__ int bins[NCLS * DG];  // 12.8 KB (clsum branch only)
    const int t = threadIdx.x;

    if (blockIdx.x < PREP_BLKS) {
        // ---------------- prep: 16 rows/block ----------------
        const int wave = t >> 6;
        const int lane = t & 63;
        #pragma unroll
        for (int it = 0; it < 4; ++it) {
            const int row = blockIdx.x * 16 + it * 4 + wave;
            const float4* rp = reinterpret_cast<const float4*>(f + (size_t)row * Cc);
            float4 v0 = rp[lane * 2 + 0];
            float4 v1 = rp[lane * 2 + 1];
            float s8 = v0.x * v0.x + v0.y * v0.y + v0.z * v0.z + v0.w * v0.w +
                       v1.x * v1.x + v1.y * v1.y + v1.z * v1.z + v1.w * v1.w;
            if (lane < 4) {   // first 32 features -> bf16 for the filter
                short8v o;
                o[0] = (short)f2bf(v0.x); o[1] = (short)f2bf(v0.y);
                o[2] = (short)f2bf(v0.z); o[3] = (short)f2bf(v0.w);
                o[4] = (short)f2bf(v1.x); o[5] = (short)f2bf(v1.y);
                o[6] = (short)f2bf(v1.z); o[7] = (short)f2bf(v1.w);
                *reinterpret_cast<short8v*>(fb32 + (size_t)row * KF + lane * 8) = o;
            }
            float sAll = s8;
            float s32  = (lane < 4) ? s8 : 0.0f;
            #pragma unroll
            for (int off = 32; off > 0; off >>= 1) {
                sAll += __shfl_down(sAll, off, 64);
                s32  += __shfl_down(s32,  off, 64);
            }
            if (lane == 0) { sq32[row] = s32; sqAll[row] = sAll; }
        }
    } else {
        // ---------------- clsum: class sums, LDS int atomics ----------------
        const int idx   = blockIdx.x - PREP_BLKS;
        const int chunk = idx >> 4;      // 0..31 (256 rows each)
        const int g     = idx & 15;      // dim group
        const int dim   = t & (DG - 1);  // 0..31
        const int rgrp  = t >> 5;        // 0..7

        for (int i = t; i < NCLS * DG; i += 256) bins[i] = 0;
        __syncthreads();

        const int r0 = chunk * 256 + rgrp * 32;
        #pragma unroll 4
        for (int r = 0; r < 32; ++r) {
            const int row = r0 + r;
            const int c   = tgt[row];
            const float x = f[(size_t)row * Cc + g * DG + dim];
            const int  iq = (int)rintf(x * SCALE_M);
            atomicAdd(&bins[c * DG + dim], iq);
        }
        __syncthreads();

        int* dst = partials + (size_t)chunk * NBINS;
        for (int i = t; i < NCLS * DG; i += 256) {
            const int c = i >> 5, d = i & (DG - 1);
            dst[c * Cc + g * DG + d] = bins[i];
        }
    }
}

// ---------------------------------------------------------------- fused2c: filter(128^2, x4 grid-stride) || msq || s2cnt
__global__ __launch_bounds__(256) void fused2c_kernel(const unsigned short* __restrict__ fb32,
                                                      const float* __restrict__ f,
                                                      const int* __restrict__ tgt,
                                                      const float* __restrict__ sq32,
                                                      const float* __restrict__ sqAll,
                                                      const int* __restrict__ partials,
                                                      double* __restrict__ negPart,
                                                      double* __restrict__ msqPart,
                                                      double* __restrict__ paPart) {
    __shared__ __align__(16) char smem[20496];   // union across segments
    const int tid = threadIdx.x;

    if (blockIdx.x < FILT_BLKS) {
        // ------------- hinge screen, 128x128 tiles, grid-stride x4 -------------
        auto As = reinterpret_cast<unsigned short (*)[40]>(smem);            // 10.24 KB
        auto Bs = reinterpret_cast<unsigned short (*)[40]>(smem + 10240);    // 10.24 KB
        float* wsum = reinterpret_cast<float*>(smem + 20480);

        const int lane = tid & 63;
        const int wid  = tid >> 6;
        const int wr   = wid >> 1;     // 0..1 (64-row slab)
        const int wc   = wid & 1;      // 0..1 (64-col slab)

        for (int unit = blockIdx.x; unit < NPAIRSF; unit += FILT_BLKS) {
            int rem = unit, br = 0;
            while (rem >= NBLKF - br) { rem -= NBLKF - br; ++br; }
            const int bc = br + rem;

            __syncthreads();   // previous tile's LDS reads done before re-stage
            #pragma unroll
            for (int it = 0; it < 2; ++it) {
                const int s   = tid + it * 256;
                const int row = s >> 2, q = s & 3;
                short8v va = *reinterpret_cast<const short8v*>(fb32 + (size_t)(br * 128 + row) * KF + q * 8);
                short8v vb = *reinterpret_cast<const short8v*>(fb32 + (size_t)(bc * 128 + row) * KF + q * 8);
                *reinterpret_cast<short8v*>(&As[row][q * 8]) = va;
                *reinterpret_cast<short8v*>(&Bs[row][q * 8]) = vb;
            }
            __syncthreads();

            const f32x4 zero = {0.f, 0.f, 0.f, 0.f};
            short8v a[4], b[4];
            #pragma unroll
            for (int mf = 0; mf < 4; ++mf) {
                const int row = wr * 64 + mf * 16 + (lane & 15);
                a[mf] = *reinterpret_cast<const short8v*>(&As[row][(lane >> 4) * 8]);
            }
            #pragma unroll
            for (int nf = 0; nf < 4; ++nf) {
                const int row = wc * 64 + nf * 16 + (lane & 15);
                b[nf] = *reinterpret_cast<const short8v*>(&Bs[row][(lane >> 4) * 8]);
            }
            f32x4 acc[4][4];
            #pragma unroll
            for (int mf = 0; mf < 4; ++mf)
                #pragma unroll
                for (int nf = 0; nf < 4; ++nf)
                    acc[mf][nf] = __builtin_amdgcn_mfma_f32_16x16x32_bf16(a[mf], b[nf], zero, 0, 0, 0);

            const int gi0 = br * 128 + wr * 64;
            const int gj0 = bc * 128 + wc * 64;

            float s32i[16]; int ti[16];
            #pragma unroll
            for (int mf = 0; mf < 4; ++mf)
                #pragma unroll
                for (int j = 0; j < 4; ++j) {
                    const int r = gi0 + mf * 16 + (lane >> 4) * 4 + j;
                    s32i[mf * 4 + j] = sq32[r];
                    ti[mf * 4 + j]   = tgt[r];
                }
            float s32j[4]; int tj[4];
            #pragma unroll
            for (int nf = 0; nf < 4; ++nf) {
                const int c = gj0 + nf * 16 + (lane & 15);
                s32j[nf] = sq32[c];
                tj[nf]   = tgt[c];
            }

            // hot loop: branchless, 64-bit hit mask (64 cells/thread)
            unsigned long long hit = 0ULL;
            #pragma unroll
            for (int mf = 0; mf < 4; ++mf)
                #pragma unroll
                for (int nf = 0; nf < 4; ++nf)
                    #pragma unroll
                    for (int j = 0; j < 4; ++j) {
                        const int r = gi0 + mf * 16 + (lane >> 4) * 4 + j;
                        const int c = gj0 + nf * 16 + (lane & 15);
                        const float d32 = s32i[mf * 4 + j] + s32j[nf] - 2.0f * acc[mf][nf][j];
                        const bool take = (r != c) & (ti[mf * 4 + j] != tj[nf]) & (d32 < FILT_THR);
                        const int cell = mf * 16 + nf * 4 + j;   // compile-time
                        hit |= take ? (1ULL << cell) : 0ULL;
                    }

            // cold path: execz-skipped when no lane has a hit
            float neg = 0.0f;
            if (hit) {
                unsigned long long m = hit;
                while (m) {
                    const int bpos = (int)__builtin_ctzll(m);
                    m &= m - 1;
                    const int mf = (bpos >> 4) & 3;
                    const int nf = (bpos >> 2) & 3;
                    const int j  = bpos & 3;
                    const int r = gi0 + mf * 16 + (lane >> 4) * 4 + j;
                    const int c = gj0 + nf * 16 + (lane & 15);
                    const float4* xr = reinterpret_cast<const float4*>(f + (size_t)r * Cc);
                    const float4* xc = reinterpret_cast<const float4*>(f + (size_t)c * Cc);
                    float dd = 0.0f;
                    for (int k = 0; k < Cc / 4; ++k) {
                        float4 aa = xr[k], bb = xc[k];
                        float dx = aa.x - bb.x, dy = aa.y - bb.y;
                        float dz = aa.z - bb.z, dw = aa.w - bb.w;
                        dd += dx * dx + dy * dy + dz * dz + dw * dw;
                    }
                    const float t = (dd > 0.0f) ? (MRG - sqrtf(dd)) : MRG;
                    if (t > 0.0f) neg += t * t;
                }
            }

            #pragma unroll
            for (int off = 32; off > 0; off >>= 1) neg += __shfl_down(neg, off, 64);
            if (lane == 0) wsum[wid] = neg;
            __syncthreads();
            if (tid == 0) {
                const float w = (br == bc) ? 1.0f : 2.0f;
                negPart[unit] = (double)(w * (wsum[0] + wsum[1] + wsum[2] + wsum[3]));
            }
        }
    } else if (blockIdx.x < FILT_BLKS + MSQ_BLKS) {
        // ---------------- msq: sum_c |M_c|^2 partials ----------------
        double* red = reinterpret_cast<double*>(smem);
        const int bid = blockIdx.x - FILT_BLKS;    // 0..255
        double local = 0.0;
        const int idx = bid * 200 + tid;
        if (tid < 200 && idx < NBINS) {
            long long ws = 0;
            #pragma unroll 8
            for (int ch = 0; ch < NCHUNK; ++ch)
                ws += (long long)partials[(size_t)ch * NBINS + idx];
            const double m = (double)ws * (1.0 / (double)SCALE_M);
            local = m * m;
        }
        red[tid] = local;
        __syncthreads();
        #pragma unroll
        for (int st = 128; st > 0; st >>= 1) {
            if (tid < st) red[tid] += red[tid + st];
            __syncthreads();
        }
        if (tid == 0) msqPart[bid] = red[0];
    } else {
        // ---------------- s2cnt: per-class S2 & count -> paPart ----------------
        unsigned long long* s2b = reinterpret_cast<unsigned long long*>(smem);   // 800 B
        int* cb = reinterpret_cast<int*>(smem + 800);                            // 400 B
        if (tid < NCLS) { s2b[tid] = 0ULL; cb[tid] = 0; }
        __syncthreads();
        for (int i = tid; i < Nn; i += 256) {
            const int c = tgt[i];
            atomicAdd(&s2b[c], (unsigned long long)(long long)(sqAll[i] * SCALE_S2));
            atomicAdd(&cb[c], 1);
        }
        __syncthreads();
        if (tid < NCLS) {
            const double n  = (double)cb[tid];
            const double s2 = (double)(long long)s2b[tid] * (1.0 / (double)SCALE_S2);
            paPart[tid] = 2.0 * n * s2;
        }
    }
}

// ---------------------------------------------------------------- final combine (tiny)
__global__ __launch_bounds__(256) void finish4_kernel(const double* __restrict__ paPart,
                                                      const double* __restrict__ msqPart,
                                                      const double* __restrict__ negPart,
                                                      float* __restrict__ out) {
    __shared__ double red[256];
    const int t = threadIdx.x;
    double v = (t < NCLS) ? paPart[t] : 0.0;   // analytic positive
    v -= 2.0 * msqPart[t];                     // -2 sum |M_c|^2 (256 entries)
    double nsum = 0.0;
    for (int i = t; i < NPAIRSF; i += 256) nsum += negPart[i];
    red[t] = v + nsum;
    __syncthreads();
    #pragma unroll
    for (int st = 128; st > 0; st >>= 1) {
        if (t < st) red[t] += red[t + st];
        __syncthreads();
    }
    if (t == 0) {
        const double T = (double)Nn * (double)(Nn - 1);
        out[0] = (float)(red[0] / (2.0 * T));
    }
}

// ---------------------------------------------------------------- fp32 fallback (round 1)
__global__ __launch_bounds__(256) void sq_kernel(const float* __restrict__ f,
                                                 float* __restrict__ sq) {
    const int wave = threadIdx.x >> 6;
    const int lane = threadIdx.x & 63;
    const int row  = blockIdx.x * 4 + wave;
    const float4* rp = reinterpret_cast<const float4*>(f + (size_t)row * Cc);
    float4 v0 = rp[lane * 2 + 0];
    float4 v1 = rp[lane * 2 + 1];
    float s = v0.x * v0.x + v0.y * v0.y + v0.z * v0.z + v0.w * v0.w +
              v1.x * v1.x + v1.y * v1.y + v1.z * v1.z + v1.w * v1.w;
    #pragma unroll
    for (int off = 32; off > 0; off >>= 1) s += __shfl_down(s, off, 64);
    if (lane == 0) sq[row] = s;
}

__global__ __launch_bounds__(256) void pair_fp32(const float* __restrict__ f,
                                                 const int* __restrict__ tgt,
                                                 const float* __restrict__ sq,
                                                 double* __restrict__ partials) {
    int rem = blockIdx.x, br = 0;
    while (rem >= NBLK1 - br) { rem -= NBLK1 - br; ++br; }
    const int bc = br + rem;

    __shared__ float As[BK1][LSTR];
    __shared__ float Bs[BK1][LSTR];
    __shared__ float red[256];

    const int tid  = threadIdx.x;
    const int tx   = tid & 15;
    const int ty   = tid >> 4;
    const int row0 = ty * 4;
    const int col0 = tx * 4;

    const float* abase = f + (size_t)br * BM1 * Cc;
    const float* bbase = f + (size_t)bc * BM1 * Cc;

    const int r0 = tid >> 3;
    const int kb = (tid & 7) * 4;

    float acc[4][4] = {};

    for (int k0 = 0; k0 < Cc; k0 += BK1) {
        float4 a0 = *reinterpret_cast<const float4*>(abase + (size_t)(r0)      * Cc + k0 + kb);
        float4 a1 = *reinterpret_cast<const float4*>(abase + (size_t)(r0 + 32) * Cc + k0 + kb);
        float4 b0 = *reinterpret_cast<const float4*>(bbase + (size_t)(r0)      * Cc + k0 + kb);
        float4 b1 = *reinterpret_cast<const float4*>(bbase + (size_t)(r0 + 32) * Cc + k0 + kb);
        __syncthreads();
        As[kb + 0][r0]      = a0.x; As[kb + 1][r0]      = a0.y;
        As[kb + 2][r0]      = a0.z; As[kb + 3][r0]      = a0.w;
        As[kb + 0][r0 + 32] = a1.x; As[kb + 1][r0 + 32] = a1.y;
        As[kb + 2][r0 + 32] = a1.z; As[kb + 3][r0 + 32] = a1.w;
        Bs[kb + 0][r0]      = b0.x; Bs[kb + 1][r0]      = b0.y;
        Bs[kb + 2][r0]      = b0.z; Bs[kb + 3][r0]      = b0.w;
        Bs[kb + 0][r0 + 32] = b1.x; Bs[kb + 1][r0 + 32] = b1.y;
        Bs[kb + 2][r0 + 32] = b1.z; Bs[kb + 3][r0 + 32] = b1.w;
        __syncthreads();
        #pragma unroll
        for (int k = 0; k < BK1; ++k) {
            float4 av = *reinterpret_cast<const float4*>(&As[k][row0]);
            float4 bv = *reinterpret_cast<const float4*>(&Bs[k][col0]);
            acc[0][0] = fmaf(av.x, bv.x, acc[0][0]);
            acc[0][1] = fmaf(av.x, bv.y, acc[0][1]);
            acc[0][2] = fmaf(av.x, bv.z, acc[0][2]);
            acc[0][3] = fmaf(av.x, bv.w, acc[0][3]);
            acc[1][0] = fmaf(av.y, bv.x, acc[1][0]);
            acc[1][1] = fmaf(av.y, bv.y, acc[1][1]);
            acc[1][2] = fmaf(av.y, bv.z, acc[1][2]);
            acc[1][3] = fmaf(av.y, bv.w, acc[1][3]);
            acc[2][0] = fmaf(av.z, bv.x, acc[2][0]);
            acc[2][1] = fmaf(av.z, bv.y, acc[2][1]);
            acc[2][2] = fmaf(av.z, bv.z, acc[2][2]);
            acc[2][3] = fmaf(av.z, bv.w, acc[2][3]);
            acc[3][0] = fmaf(av.w, bv.x, acc[3][0]);
            acc[3][1] = fmaf(av.w, bv.y, acc[3][1]);
            acc[3][2] = fmaf(av.w, bv.z, acc[3][2]);
            acc[3][3] = fmaf(av.w, bv.w, acc[3][3]);
        }
    }

    const int gi = br * BM1 + row0;
    const int gj = bc * BM1 + col0;
    float sqi[4], sqj[4];
    int   ti_[4], tj_[4];
    #pragma unroll
    for (int m = 0; m < 4; ++m) { sqi[m] = sq[gi + m]; ti_[m] = tgt[gi + m]; }
    #pragma unroll
    for (int n = 0; n < 4; ++n) { sqj[n] = sq[gj + n]; tj_[n] = tgt[gj + n]; }

    float pos = 0.f, neg = 0.f;
    #pragma unroll
    for (int m = 0; m < 4; ++m)
        #pragma unroll
        for (int n = 0; n < 4; ++n) {
            if (gi + m == gj + n) continue;
            float d = fmaxf(sqi[m] + sqj[n] - 2.0f * acc[m][n], 0.0f);
            if (ti_[m] == tj_[n]) pos += d;
            else if (d < 1.0f) { float t = MRG - sqrtf(d); neg += t * t; }
        }
    const float w = (br == bc) ? 1.0f : 2.0f;
    red[tid] = w * (pos + neg);
    __syncthreads();
    #pragma unroll
    for (int st = 128; st > 0; st >>= 1) {
        if (tid < st) red[tid] += red[tid + st];
        __syncthreads();
    }
    if (tid == 0) partials[blockIdx.x] = (double)red[0];
}

__global__ __launch_bounds__(256) void finish_kernel(const double* __restrict__ partials,
                                                     float* __restrict__ out, int n) {
    __shared__ double red[256];
    double s = 0.0;
    for (int i = threadIdx.x; i < n; i += 256) s += partials[i];
    red[threadIdx.x] = s;
    __syncthreads();
    #pragma unroll
    for (int st = 128; st > 0; st >>= 1) {
        if (threadIdx.x < st) red[threadIdx.x] += red[threadIdx.x + st];
        __syncthreads();
    }
    if (threadIdx.x == 0) {
        const double t = (double)Nn * (double)(Nn - 1);
        out[0] = (float)(red[0] / (2.0 * t));
    }
}

// ---------------------------------------------------------------- launch
extern "C" void kernel_launch(void* const* d_in, const int* in_sizes, int n_in,
                              void* d_out, int out_size, void* d_ws, size_t ws_size,
                              hipStream_t stream) {
    const float* f   = (const float*)d_in[0];
    const int*   tgt = (const int*)d_in[1];
    float*       out = (float*)d_out;

    // workspace layout (16B-aligned)
    const size_t off_fb32  = 0;                                      // 512 KB
    const size_t off_sq32  = off_fb32  + (size_t)Nn * KF * 2;        // 32 KB
    const size_t off_sqAll = off_sq32  + (size_t)Nn * 4;             // 32 KB
    const size_t off_part  = off_sqAll + (size_t)Nn * 4;             // 32*51200*4 = 6.55 MB
    const size_t off_msq   = off_part  + (size_t)NCHUNK * NBINS * 4; // 256*8
    const size_t off_neg   = off_msq   + (size_t)256 * 8;            // 2080*8
    const size_t off_pa    = off_neg   + (size_t)NPAIRSF * 8;        // 128*8
    const size_t needed    = off_pa    + (size_t)128 * 8;            // ~7.2 MB

    if (ws_size >= needed) {
        unsigned short* fb32 = (unsigned short*)((char*)d_ws + off_fb32);
        float*  sq32         = (float*) ((char*)d_ws + off_sq32);
        float*  sqAll        = (float*) ((char*)d_ws + off_sqAll);
        int*    partials     = (int*)   ((char*)d_ws + off_part);
        double* msqPart      = (double*)((char*)d_ws + off_msq);
        double* negPart      = (double*)((char*)d_ws + off_neg);
        double* paPart       = (double*)((char*)d_ws + off_pa);

        hipLaunchKernelGGL(fused1_kernel,  dim3(PREP_BLKS + CLSUM_BLKS), dim3(256), 0, stream,
                           f, tgt, fb32, sq32, sqAll, partials);
        hipLaunchKernelGGL(fused2c_kernel, dim3(F2_BLKS),                dim3(256), 0, stream,
                           fb32, f, tgt, sq32, sqAll, partials, negPart, msqPart, paPart);
        hipLaunchKernelGGL(finish4_kernel, dim3(1),                      dim3(256), 0, stream,
                           paPart, msqPart, negPart, out);
    } else {
        float*  sq       = (float*)d_ws;
        double* partials = (double*)((char*)d_ws + (size_t)Nn * sizeof(float));

        hipLaunchKernelGGL(sq_kernel,     dim3(Nn / 4),  dim3(256), 0, stream, f, sq);
        hipLaunchKernelGGL(pair_fp32,     dim3(NPAIRS1), dim3(256), 0, stream, f, tgt, sq, partials);
        hipLaunchKernelGGL(finish_kernel, dim3(1),       dim3(256), 0, stream, partials, out, NPAIRS1);
    }
}

// Round 15
// 35.404 us; speedup vs baseline: 1.3323x; 1.3323x over previous
//
#include <hip/hip_runtime.h>
#include <math.h>
#include <stdint.h>

// ContrastiveLoss: N=8192, C=512, NC=100, MARGIN=1.0
// loss = (sum_{i!=j,same} d_ij + sum_{i!=j,diff} max(0, 1-sqrt(d_ij))^2) / (2*N*(N-1))
// d_ij = |xi|^2+|xj|^2-2 xi.xj (clamped at 0).
//
// Round 15: R13 geometry (best, 44.7us; R14 grid-stride probe regressed) with
// SEGMENT REORDERING for tail overlap: long-pole latency-bound segments get
// the LOWEST block IDs so they start first and overlap the bulk segment:
//   fused1: clsum (512 blks, 32-iter loops) first, then prep (2048).
//   fused2: s2cnt (1 blk, 32-iter) + msq (256) first, then filter (2080).
// Pure blockIdx permutation -> bit-identical result to R13.

static constexpr int   Nn  = 8192;
static constexpr int   Cc  = 512;
static constexpr float MRG = 1.0f;
static constexpr int   KF  = 32;          // filter features
static constexpr float FILT_THR = 2.0f;   // margin^2 + bf16-error slack

static constexpr int NBLKF   = Nn / 128;                  // 64
static constexpr int NPAIRSF = NBLKF * (NBLKF + 1) / 2;   // 2080
static constexpr int NCLS    = 100;
static constexpr int NBINS   = NCLS * Cc;                 // 51200

static constexpr int NCHUNK  = 32;        // row chunks (256 rows each)
static constexpr int DG      = 32;        // dims per group
static constexpr int NDG     = Cc / DG;   // 16 dim groups

static constexpr int PREP_BLKS  = Nn / 4;          // 2048
static constexpr int CLSUM_BLKS = NCHUNK * NDG;    // 512
static constexpr int MSQ_BLKS   = 256;             // 200 bins each
static constexpr int F2_BLKS    = NPAIRSF + MSQ_BLKS + 1;   // 2337

static constexpr float SCALE_M  = 65536.0f;     // Q16 (int32 bins)
static constexpr float SCALE_S2 = 1048576.0f;   // Q20 (int64)

// ---- fp32 fallback config (small-ws path) ----
static constexpr int BM1     = 64;
static constexpr int BK1     = 32;
static constexpr int NBLK1   = Nn / BM1;
static constexpr int NPAIRS1 = NBLK1 * (NBLK1 + 1) / 2;
static constexpr int LSTR    = 68;

typedef __attribute__((ext_vector_type(8))) short short8v;
typedef __attribute__((ext_vector_type(4))) float f32x4;

static __device__ inline unsigned short f2bf(float x) {
    unsigned u = __float_as_uint(x);
    unsigned rnd = 0x7FFFu + ((u >> 16) & 1u);
    return (unsigned short)((u + rnd) >> 16);
}

// ---------------------------------------------------------------- fused1: clsum || prep  (clsum first)
__global__ __launch_bounds__(256) void fused1_kernel(const float* __restrict__ f,
                                                     const int* __restrict__ tgt,
                                                     unsigned short* __restrict__ fb32,
                                                     float* __restrict__ sq32,
                                                     float* __restrict__ sqAll,
                                                     int* __restrict__ partials) {
    __shared__ int bins[NCLS * DG];  // 12.8 KB (clsum branch only)
    const int t = threadIdx.x;

    if (blockIdx.x < CLSUM_BLKS) {
        // ---------------- clsum: class sums, LDS int atomics ----------------
        const int idx   = blockIdx.x;
        const int chunk = idx >> 4;      // 0..31 (256 rows each)
        const int g     = idx & 15;      // dim group
        const int dim   = t & (DG - 1);  // 0..31
        const int rgrp  = t >> 5;        // 0..7

        for (int i = t; i < NCLS * DG; i += 256) bins[i] = 0;
        __syncthreads();

        const int r0 = chunk * 256 + rgrp * 32;
        #pragma unroll 4
        for (int r = 0; r < 32; ++r) {
            const int row = r0 + r;
            const int c   = tgt[row];
            const float x = f[(size_t)row * Cc + g * DG + dim];
            const int  iq = (int)rintf(x * SCALE_M);
            atomicAdd(&bins[c * DG + dim], iq);
        }
        __syncthreads();

        int* dst = partials + (size_t)chunk * NBINS;
        for (int i = t; i < NCLS * DG; i += 256) {
            const int c = i >> 5, d = i & (DG - 1);
            dst[c * Cc + g * DG + d] = bins[i];
        }
    } else {
        // ---------------- prep: sq32, sqAll, fb32 ----------------
        const int blk  = blockIdx.x - CLSUM_BLKS;   // 0..2047
        const int wave = t >> 6;
        const int lane = t & 63;
        const int row  = blk * 4 + wave;
        const float4* rp = reinterpret_cast<const float4*>(f + (size_t)row * Cc);
        float4 v0 = rp[lane * 2 + 0];
        float4 v1 = rp[lane * 2 + 1];
        float s8 = v0.x * v0.x + v0.y * v0.y + v0.z * v0.z + v0.w * v0.w +
                   v1.x * v1.x + v1.y * v1.y + v1.z * v1.z + v1.w * v1.w;
        if (lane < 4) {   // first 32 features -> bf16 for the filter
            short8v o;
            o[0] = (short)f2bf(v0.x); o[1] = (short)f2bf(v0.y);
            o[2] = (short)f2bf(v0.z); o[3] = (short)f2bf(v0.w);
            o[4] = (short)f2bf(v1.x); o[5] = (short)f2bf(v1.y);
            o[6] = (short)f2bf(v1.z); o[7] = (short)f2bf(v1.w);
            *reinterpret_cast<short8v*>(fb32 + (size_t)row * KF + lane * 8) = o;
        }
        float sAll = s8;
        float s32  = (lane < 4) ? s8 : 0.0f;
        #pragma unroll
        for (int off = 32; off > 0; off >>= 1) {
            sAll += __shfl_down(sAll, off, 64);
            s32  += __shfl_down(s32,  off, 64);
        }
        if (lane == 0) { sq32[row] = s32; sqAll[row] = sAll; }
    }
}

// ---------------------------------------------------------------- fused2d: s2cnt || msq || filter (filter last)
__global__ __launch_bounds__(256) void fused2d_kernel(const unsigned short* __restrict__ fb32,
                                                      const float* __restrict__ f,
                                                      const int* __restrict__ tgt,
                                                      const float* __restrict__ sq32,
                                                      const float* __restrict__ sqAll,
                                                      const int* __restrict__ partials,
                                                      double* __restrict__ negPart,
                                                      double* __restrict__ msqPart,
                                                      double* __restrict__ paPart) {
    __shared__ __align__(16) char smem[20496];   // union across segments
    const int tid = threadIdx.x;

    if (blockIdx.x == 0) {
        // ---------------- s2cnt: per-class S2 & count -> paPart ----------------
        unsigned long long* s2b = reinterpret_cast<unsigned long long*>(smem);   // 800 B
        int* cb = reinterpret_cast<int*>(smem + 800);                            // 400 B
        if (tid < NCLS) { s2b[tid] = 0ULL; cb[tid] = 0; }
        __syncthreads();
        for (int i = tid; i < Nn; i += 256) {
            const int c = tgt[i];
            atomicAdd(&s2b[c], (unsigned long long)(long long)(sqAll[i] * SCALE_S2));
            atomicAdd(&cb[c], 1);
        }
        __syncthreads();
        if (tid < NCLS) {
            const double n  = (double)cb[tid];
            const double s2 = (double)(long long)s2b[tid] * (1.0 / (double)SCALE_S2);
            paPart[tid] = 2.0 * n * s2;
        }
    } else if (blockIdx.x <= MSQ_BLKS) {
        // ---------------- msq: sum_c |M_c|^2 partials ----------------
        double* red = reinterpret_cast<double*>(smem);
        const int bid = blockIdx.x - 1;    // 0..255
        double local = 0.0;
        const int idx = bid * 200 + tid;
        if (tid < 200 && idx < NBINS) {
            long long ws = 0;
            #pragma unroll 8
            for (int ch = 0; ch < NCHUNK; ++ch)
                ws += (long long)partials[(size_t)ch * NBINS + idx];
            const double m = (double)ws * (1.0 / (double)SCALE_M);
            local = m * m;
        }
        red[tid] = local;
        __syncthreads();
        #pragma unroll
        for (int st = 128; st > 0; st >>= 1) {
            if (tid < st) red[tid] += red[tid + st];
            __syncthreads();
        }
        if (tid == 0) msqPart[bid] = red[0];
    } else {
        // ------------- hinge screen, 128x128 tile, K=32 bf16 MFMA -------------
        auto As = reinterpret_cast<unsigned short (*)[40]>(smem);            // 10.24 KB
        auto Bs = reinterpret_cast<unsigned short (*)[40]>(smem + 10240);    // 10.24 KB
        float* wsum = reinterpret_cast<float*>(smem + 20480);

        const int unit = blockIdx.x - (MSQ_BLKS + 1);   // 0..2079
        int rem = unit, br = 0;
        while (rem >= NBLKF - br) { rem -= NBLKF - br; ++br; }
        const int bc = br + rem;

        const int lane = tid & 63;
        const int wid  = tid >> 6;
        const int wr   = wid >> 1;     // 0..1 (64-row slab)
        const int wc   = wid & 1;      // 0..1 (64-col slab)

        // stage both 128x32 bf16 tiles (8KB each): 512 slots of 16B, 2/thread
        #pragma unroll
        for (int it = 0; it < 2; ++it) {
            const int s   = tid + it * 256;
            const int row = s >> 2, q = s & 3;
            short8v va = *reinterpret_cast<const short8v*>(fb32 + (size_t)(br * 128 + row) * KF + q * 8);
            short8v vb = *reinterpret_cast<const short8v*>(fb32 + (size_t)(bc * 128 + row) * KF + q * 8);
            *reinterpret_cast<short8v*>(&As[row][q * 8]) = va;
            *reinterpret_cast<short8v*>(&Bs[row][q * 8]) = vb;
        }
        __syncthreads();

        const f32x4 zero = {0.f, 0.f, 0.f, 0.f};
        short8v a[4], b[4];
        #pragma unroll
        for (int mf = 0; mf < 4; ++mf) {
            const int row = wr * 64 + mf * 16 + (lane & 15);
            a[mf] = *reinterpret_cast<const short8v*>(&As[row][(lane >> 4) * 8]);
        }
        #pragma unroll
        for (int nf = 0; nf < 4; ++nf) {
            const int row = wc * 64 + nf * 16 + (lane & 15);
            b[nf] = *reinterpret_cast<const short8v*>(&Bs[row][(lane >> 4) * 8]);
        }
        f32x4 acc[4][4];
        #pragma unroll
        for (int mf = 0; mf < 4; ++mf)
            #pragma unroll
            for (int nf = 0; nf < 4; ++nf)
                acc[mf][nf] = __builtin_amdgcn_mfma_f32_16x16x32_bf16(a[mf], b[nf], zero, 0, 0, 0);

        const int gi0 = br * 128 + wr * 64;
        const int gj0 = bc * 128 + wc * 64;

        float s32i[16]; int ti[16];
        #pragma unroll
        for (int mf = 0; mf < 4; ++mf)
            #pragma unroll
            for (int j = 0; j < 4; ++j) {
                const int r = gi0 + mf * 16 + (lane >> 4) * 4 + j;
                s32i[mf * 4 + j] = sq32[r];
                ti[mf * 4 + j]   = tgt[r];
            }
        float s32j[4]; int tj[4];
        #pragma unroll
        for (int nf = 0; nf < 4; ++nf) {
            const int c = gj0 + nf * 16 + (lane & 15);
            s32j[nf] = sq32[c];
            tj[nf]   = tgt[c];
        }

        // hot loop: branchless, 64-bit hit mask (64 cells/thread)
        unsigned long long hit = 0ULL;
        #pragma unroll
        for (int mf = 0; mf < 4; ++mf)
            #pragma unroll
            for (int nf = 0; nf < 4; ++nf)
                #pragma unroll
                for (int j = 0; j < 4; ++j) {
                    const int r = gi0 + mf * 16 + (lane >> 4) * 4 + j;
                    const int c = gj0 + nf * 16 + (lane & 15);
                    const float d32 = s32i[mf * 4 + j] + s32j[nf] - 2.0f * acc[mf][nf][j];
                    const bool take = (r != c) & (ti[mf * 4 + j] != tj[nf]) & (d32 < FILT_THR);
                    const int cell = mf * 16 + nf * 4 + j;   // compile-time
                    hit |= take ? (1ULL << cell) : 0ULL;
                }

        // cold path: execz-skipped when no lane has a hit
        float neg = 0.0f;
        if (hit) {
            unsigned long long m = hit;
            while (m) {
                const int bpos = (int)__builtin_ctzll(m);
                m &= m - 1;
                const int mf = (bpos >> 4) & 3;
                const int nf = (bpos >> 2) & 3;
                const int j  = bpos & 3;
                const int r = gi0 + mf * 16 + (lane >> 4) * 4 + j;
                const int c = gj0 + nf * 16 + (lane & 15);
                const float4* xr = reinterpret_cast<const float4*>(f + (size_t)r * Cc);
                const float4* xc = reinterpret_cast<const float4*>(f + (size_t)c * Cc);
                float dd = 0.0f;
                for (int k = 0; k < Cc / 4; ++k) {
                    float4 aa = xr[k], bb = xc[k];
                    float dx = aa.x - bb.x, dy = aa.y - bb.y;
                    float dz = aa.z - bb.z, dw = aa.w - bb.w;
                    dd += dx * dx + dy * dy + dz * dz + dw * dw;
                }
                const float t = (dd > 0.0f) ? (MRG - sqrtf(dd)) : MRG;
                if (t > 0.0f) neg += t * t;
            }
        }

        #pragma unroll
        for (int off = 32; off > 0; off >>= 1) neg += __shfl_down(neg, off, 64);
        if (lane == 0) wsum[wid] = neg;
        __syncthreads();
        if (tid == 0) {
            const float w = (br == bc) ? 1.0f : 2.0f;
            negPart[unit] = (double)(w * (wsum[0] + wsum[1] + wsum[2] + wsum[3]));
        }
    }
}

// ---------------------------------------------------------------- final combine (tiny)
__global__ __launch_bounds__(256) void finish4_kernel(const double* __restrict__ paPart,
                                                      const double* __restrict__ msqPart,
                                                      const double* __restrict__ negPart,
                                                      float* __restrict__ out) {
    __shared__ double red[256];
    const int t = threadIdx.x;
    double v = (t < NCLS) ? paPart[t] : 0.0;   // analytic positive
    v -= 2.0 * msqPart[t];                     // -2 sum |M_c|^2 (256 entries)
    double nsum = 0.0;
    for (int i = t; i < NPAIRSF; i += 256) nsum += negPart[i];
    red[t] = v + nsum;
    __syncthreads();
    #pragma unroll
    for (int st = 128; st > 0; st >>= 1) {
        if (t < st) red[t] += red[t + st];
        __syncthreads();
    }
    if (t == 0) {
        const double T = (double)Nn * (double)(Nn - 1);
        out[0] = (float)(red[0] / (2.0 * T));
    }
}

// ---------------------------------------------------------------- fp32 fallback (round 1)
__global__ __launch_bounds__(256) void sq_kernel(const float* __restrict__ f,
                                                 float* __restrict__ sq) {
    const int wave = threadIdx.x >> 6;
    const int lane = threadIdx.x & 63;
    const int row  = blockIdx.x * 4 + wave;
    const float4* rp = reinterpret_cast<const float4*>(f + (size_t)row * Cc);
    float4 v0 = rp[lane * 2 + 0];
    float4 v1 = rp[lane * 2 + 1];
    float s = v0.x * v0.x + v0.y * v0.y + v0.z * v0.z + v0.w * v0.w +
              v1.x * v1.x + v1.y * v1.y + v1.z * v1.z + v1.w * v1.w;
    #pragma unroll
    for (int off = 32; off > 0; off >>= 1) s += __shfl_down(s, off, 64);
    if (lane == 0) sq[row] = s;
}

__global__ __launch_bounds__(256) void pair_fp32(const float* __restrict__ f,
                                                 const int* __restrict__ tgt,
                                                 const float* __restrict__ sq,
                                                 double* __restrict__ partials) {
    int rem = blockIdx.x, br = 0;
    while (rem >= NBLK1 - br) { rem -= NBLK1 - br; ++br; }
    const int bc = br + rem;

    __shared__ float As[BK1][LSTR];
    __shared__ float Bs[BK1][LSTR];
    __shared__ float red[256];

    const int tid  = threadIdx.x;
    const int tx   = tid & 15;
    const int ty   = tid >> 4;
    const int row0 = ty * 4;
    const int col0 = tx * 4;

    const float* abase = f + (size_t)br * BM1 * Cc;
    const float* bbase = f + (size_t)bc * BM1 * Cc;

    const int r0 = tid >> 3;
    const int kb = (tid & 7) * 4;

    float acc[4][4] = {};

    for (int k0 = 0; k0 < Cc; k0 += BK1) {
        float4 a0 = *reinterpret_cast<const float4*>(abase + (size_t)(r0)      * Cc + k0 + kb);
        float4 a1 = *reinterpret_cast<const float4*>(abase + (size_t)(r0 + 32) * Cc + k0 + kb);
        float4 b0 = *reinterpret_cast<const float4*>(bbase + (size_t)(r0)      * Cc + k0 + kb);
        float4 b1 = *reinterpret_cast<const float4*>(bbase + (size_t)(r0 + 32) * Cc + k0 + kb);
        __syncthreads();
        As[kb + 0][r0]      = a0.x; As[kb + 1][r0]      = a0.y;
        As[kb + 2][r0]      = a0.z; As[kb + 3][r0]      = a0.w;
        As[kb + 0][r0 + 32] = a1.x; As[kb + 1][r0 + 32] = a1.y;
        As[kb + 2][r0 + 32] = a1.z; As[kb + 3][r0 + 32] = a1.w;
        Bs[kb + 0][r0]      = b0.x; Bs[kb + 1][r0]      = b0.y;
        Bs[kb + 2][r0]      = b0.z; Bs[kb + 3][r0]      = b0.w;
        Bs[kb + 0][r0 + 32] = b1.x; Bs[kb + 1][r0 + 32] = b1.y;
        Bs[kb + 2][r0 + 32] = b1.z; Bs[kb + 3][r0 + 32] = b1.w;
        __syncthreads();
        #pragma unroll
        for (int k = 0; k < BK1; ++k) {
            float4 av = *reinterpret_cast<const float4*>(&As[k][row0]);
            float4 bv = *reinterpret_cast<const float4*>(&Bs[k][col0]);
            acc[0][0] = fmaf(av.x, bv.x, acc[0][0]);
            acc[0][1] = fmaf(av.x, bv.y, acc[0][1]);
            acc[0][2] = fmaf(av.x, bv.z, acc[0][2]);
            acc[0][3] = fmaf(av.x, bv.w, acc[0][3]);
            acc[1][0] = fmaf(av.y, bv.x, acc[1][0]);
            acc[1][1] = fmaf(av.y, bv.y, acc[1][1]);
            acc[1][2] = fmaf(av.y, bv.z, acc[1][2]);
            acc[1][3] = fmaf(av.y, bv.w, acc[1][3]);
            acc[2][0] = fmaf(av.z, bv.x, acc[2][0]);
            acc[2][1] = fmaf(av.z, bv.y, acc[2][1]);
            acc[2][2] = fmaf(av.z, bv.z, acc[2][2]);
            acc[2][3] = fmaf(av.z, bv.w, acc[2][3]);
            acc[3][0] = fmaf(av.w, bv.x, acc[3][0]);
            acc[3][1] = fmaf(av.w, bv.y, acc[3][1]);
            acc[3][2] = fmaf(av.w, bv.z, acc[3][2]);
            acc[3][3] = fmaf(av.w, bv.w, acc[3][3]);
        }
    }

    const int gi = br * BM1 + row0;
    const int gj = bc * BM1 + col0;
    float sqi[4], sqj[4];
    int   ti_[4], tj_[4];
    #pragma unroll
    for (int m = 0; m < 4; ++m) { sqi[m] = sq[gi + m]; ti_[m] = tgt[gi + m]; }
    #pragma unroll
    for (int n = 0; n < 4; ++n) { sqj[n] = sq[gj + n]; tj_[n] = tgt[gj + n]; }

    float pos = 0.f, neg = 0.f;
    #pragma unroll
    for (int m = 0; m < 4; ++m)
        #pragma unroll
        for (int n = 0; n < 4; ++n) {
            if (gi + m == gj + n) continue;
            float d = fmaxf(sqi[m] + sqj[n] - 2.0f * acc[m][n], 0.0f);
            if (ti_[m] == tj_[n]) pos += d;
            else if (d < 1.0f) { float t = MRG - sqrtf(d); neg += t * t; }
        }
    const float w = (br == bc) ? 1.0f : 2.0f;
    red[tid] = w * (pos + neg);
    __syncthreads();
    #pragma unroll
    for (int st = 128; st > 0; st >>= 1) {
        if (tid < st) red[tid] += red[tid + st];
        __syncthreads();
    }
    if (tid == 0) partials[blockIdx.x] = (double)red[0];
}

__global__ __launch_bounds__(256) void finish_kernel(const double* __restrict__ partials,
                                                     float* __restrict__ out, int n) {
    __shared__ double red[256];
    double s = 0.0;
    for (int i = threadIdx.x; i < n; i += 256) s += partials[i];
    red[threadIdx.x] = s;
    __syncthreads();
    #pragma unroll
    for (int st = 128; st > 0; st >>= 1) {
        if (threadIdx.x < st) red[threadIdx.x] += red[threadIdx.x + st];
        __syncthreads();
    }
    if (threadIdx.x == 0) {
        const double t = (double)Nn * (double)(Nn - 1);
        out[0] = (float)(red[0] / (2.0 * t));
    }
}

// ---------------------------------------------------------------- launch
extern "C" void kernel_launch(void* const* d_in, const int* in_sizes, int n_in,
                              void* d_out, int out_size, void* d_ws, size_t ws_size,
                              hipStream_t stream) {
    const float* f   = (const float*)d_in[0];
    const int*   tgt = (const int*)d_in[1];
    float*       out = (float*)d_out;

    // workspace layout (16B-aligned)
    const size_t off_fb32  = 0;                                      // 512 KB
    const size_t off_sq32  = off_fb32  + (size_t)Nn * KF * 2;        // 32 KB
    const size_t off_sqAll = off_sq32  + (size_t)Nn * 4;             // 32 KB
    const size_t off_part  = off_sqAll + (size_t)Nn * 4;             // 32*51200*4 = 6.55 MB
    const size_t off_msq   = off_part  + (size_t)NCHUNK * NBINS * 4; // 256*8
    const size_t off_neg   = off_msq   + (size_t)256 * 8;            // 2080*8
    const size_t off_pa    = off_neg   + (size_t)NPAIRSF * 8;        // 128*8
    const size_t needed    = off_pa    + (size_t)128 * 8;            // ~7.2 MB

    if (ws_size >= needed) {
        unsigned short* fb32 = (unsigned short*)((char*)d_ws + off_fb32);
        float*  sq32         = (float*) ((char*)d_ws + off_sq32);
        float*  sqAll        = (float*) ((char*)d_ws + off_sqAll);
        int*    partials     = (int*)   ((char*)d_ws + off_part);
        double* msqPart      = (double*)((char*)d_ws + off_msq);
        double* negPart      = (double*)((char*)d_ws + off_neg);
        double* paPart       = (double*)((char*)d_ws + off_pa);

        hipLaunchKernelGGL(fused1_kernel,  dim3(PREP_BLKS + CLSUM_BLKS), dim3(256), 0, stream,
                           f, tgt, fb32, sq32, sqAll, partials);
        hipLaunchKernelGGL(fused2d_kernel, dim3(F2_BLKS),                dim3(256), 0, stream,
                           fb32, f, tgt, sq32, sqAll, partials, negPart, msqPart, paPart);
        hipLaunchKernelGGL(finish4_kernel, dim3(1),                      dim3(256), 0, stream,
                           paPart, msqPart, negPart, out);
    } else {
        float*  sq       = (float*)d_ws;
        double* partials = (double*)((char*)d_ws + (size_t)Nn * sizeof(float));

        hipLaunchKernelGGL(sq_kernel,     dim3(Nn / 4),  dim3(256), 0, stream, f, sq);
        hipLaunchKernelGGL(pair_fp32,     dim3(NPAIRS1), dim3(256), 0, stream, f, tgt, sq, partials);
        hipLaunchKernelGGL(finish_kernel, dim3(1),       dim3(256), 0, stream, partials, out, NPAIRS1);
    }
}

// Round 16
// 35.303 us; speedup vs baseline: 1.3361x; 1.0029x over previous
//
#include <hip/hip_runtime.h>
#include <math.h>
#include <stdint.h>

// ContrastiveLoss: N=8192, C=512, NC=100, MARGIN=1.0
// loss = (sum_{i!=j,same} d_ij + sum_{i!=j,diff} max(0, 1-sqrt(d_ij))^2) / (2*N*(N-1))
// d_ij = |xi|^2+|xj|^2-2 xi.xj (clamped at 0).
//
// Round 16: R15 structure (clsum-first / filter-last ordering, 35.4us) with
// two latency-pole fixes:
//  - clsum: DG=64 + float2 loads (8B/lane full-width waves, half the load
//    instructions; paired LDS atomics = free 2-way banks). 256 blocks.
//  - s2cnt: 1 block x 32 iters -> 8 blocks x 4 iters, exact int64 partials
//    summed in fixed order by finish4 (integer adds commute, bit-identical).

static constexpr int   Nn  = 8192;
static constexpr int   Cc  = 512;
static constexpr float MRG = 1.0f;
static constexpr int   KF  = 32;          // filter features
static constexpr float FILT_THR = 2.0f;   // margin^2 + bf16-error slack

static constexpr int NBLKF   = Nn / 128;                  // 64
static constexpr int NPAIRSF = NBLKF * (NBLKF + 1) / 2;   // 2080
static constexpr int NCLS    = 100;
static constexpr int NBINS   = NCLS * Cc;                 // 51200

static constexpr int NCHUNK  = 32;        // row chunks (256 rows each)
static constexpr int DG      = 64;        // dims per group (float2/lane)
static constexpr int NDG     = Cc / DG;   // 8 dim groups

static constexpr int PREP_BLKS  = Nn / 4;          // 2048
static constexpr int CLSUM_BLKS = NCHUNK * NDG;    // 256
static constexpr int MSQ_BLKS   = 256;             // 200 bins each
static constexpr int S2_BLKS    = 8;               // 1024 rows each
static constexpr int F2_BLKS    = S2_BLKS + MSQ_BLKS + NPAIRSF;   // 2344

static constexpr float SCALE_M  = 65536.0f;     // Q16 (int32 bins)
static constexpr float SCALE_S2 = 1048576.0f;   // Q20 (int64)

// ---- fp32 fallback config (small-ws path) ----
static constexpr int BM1     = 64;
static constexpr int BK1     = 32;
static constexpr int NBLK1   = Nn / BM1;
static constexpr int NPAIRS1 = NBLK1 * (NBLK1 + 1) / 2;
static constexpr int LSTR    = 68;

typedef __attribute__((ext_vector_type(8))) short short8v;
typedef __attribute__((ext_vector_type(4))) float f32x4;

static __device__ inline unsigned short f2bf(float x) {
    unsigned u = __float_as_uint(x);
    unsigned rnd = 0x7FFFu + ((u >> 16) & 1u);
    return (unsigned short)((u + rnd) >> 16);
}

// ---------------------------------------------------------------- fused1: clsum || prep  (clsum first)
__global__ __launch_bounds__(256) void fused1_kernel(const float* __restrict__ f,
                                                     const int* __restrict__ tgt,
                                                     unsigned short* __restrict__ fb32,
                                                     float* __restrict__ sq32,
                                                     float* __restrict__ sqAll,
                                                     int* __restrict__ partials) {
    __shared__ int bins[NCLS * DG];  // 25.6 KB (clsum branch only)
    const int t = threadIdx.x;

    if (blockIdx.x < CLSUM_BLKS) {
        // ---------------- clsum: class sums, float2 loads, LDS int atomics ----------------
        const int idx   = blockIdx.x;
        const int chunk = idx >> 3;      // 0..31 (256 rows each)
        const int g     = idx & 7;       // dim group (64 dims)
        const int dpair = (t & 31) * 2;  // dims dpair, dpair+1
        const int rgrp  = t >> 5;        // 0..7 (32 rows each)

        for (int i = t; i < NCLS * DG; i += 256) bins[i] = 0;
        __syncthreads();

        const int r0 = chunk * 256 + rgrp * 32;
        #pragma unroll 4
        for (int r = 0; r < 32; ++r) {
            const int row = r0 + r;
            const int c   = tgt[row];
            const float2 x = *reinterpret_cast<const float2*>(
                f + (size_t)row * Cc + g * DG + dpair);
            atomicAdd(&bins[c * DG + dpair + 0], (int)rintf(x.x * SCALE_M));
            atomicAdd(&bins[c * DG + dpair + 1], (int)rintf(x.y * SCALE_M));
        }
        __syncthreads();

        int* dst = partials + (size_t)chunk * NBINS;
        for (int i = t; i < NCLS * DG; i += 256) {
            const int c = i >> 6, d = i & (DG - 1);
            dst[c * Cc + g * DG + d] = bins[i];
        }
    } else {
        // ---------------- prep: sq32, sqAll, fb32 ----------------
        const int blk  = blockIdx.x - CLSUM_BLKS;   // 0..2047
        const int wave = t >> 6;
        const int lane = t & 63;
        const int row  = blk * 4 + wave;
        const float4* rp = reinterpret_cast<const float4*>(f + (size_t)row * Cc);
        float4 v0 = rp[lane * 2 + 0];
        float4 v1 = rp[lane * 2 + 1];
        float s8 = v0.x * v0.x + v0.y * v0.y + v0.z * v0.z + v0.w * v0.w +
                   v1.x * v1.x + v1.y * v1.y + v1.z * v1.z + v1.w * v1.w;
        if (lane < 4) {   // first 32 features -> bf16 for the filter
            short8v o;
            o[0] = (short)f2bf(v0.x); o[1] = (short)f2bf(v0.y);
            o[2] = (short)f2bf(v0.z); o[3] = (short)f2bf(v0.w);
            o[4] = (short)f2bf(v1.x); o[5] = (short)f2bf(v1.y);
            o[6] = (short)f2bf(v1.z); o[7] = (short)f2bf(v1.w);
            *reinterpret_cast<short8v*>(fb32 + (size_t)row * KF + lane * 8) = o;
        }
        float sAll = s8;
        float s32  = (lane < 4) ? s8 : 0.0f;
        #pragma unroll
        for (int off = 32; off > 0; off >>= 1) {
            sAll += __shfl_down(sAll, off, 64);
            s32  += __shfl_down(s32,  off, 64);
        }
        if (lane == 0) { sq32[row] = s32; sqAll[row] = sAll; }
    }
}

// ---------------------------------------------------------------- fused2e: s2cnt8 || msq || filter (filter last)
__global__ __launch_bounds__(256) void fused2e_kernel(const unsigned short* __restrict__ fb32,
                                                      const float* __restrict__ f,
                                                      const int* __restrict__ tgt,
                                                      const float* __restrict__ sq32,
                                                      const float* __restrict__ sqAll,
                                                      const int* __restrict__ partials,
                                                      double* __restrict__ negPart,
                                                      double* __restrict__ msqPart,
                                                      long long* __restrict__ s2fixPart,
                                                      int* __restrict__ cntPart) {
    __shared__ __align__(16) char smem[20496];   // union across segments
    const int tid = threadIdx.x;

    if (blockIdx.x < S2_BLKS) {
        // ---------------- s2cnt: per-class S2 & count partials (8 blocks) ----------------
        unsigned long long* s2b = reinterpret_cast<unsigned long long*>(smem);   // 800 B
        int* cb = reinterpret_cast<int*>(smem + 800);                            // 400 B
        if (tid < NCLS) { s2b[tid] = 0ULL; cb[tid] = 0; }
        __syncthreads();
        const int r0 = blockIdx.x * (Nn / S2_BLKS);       // 1024 rows
        for (int i = tid; i < Nn / S2_BLKS; i += 256) {   // 4 iters
            const int row = r0 + i;
            const int c = tgt[row];
            atomicAdd(&s2b[c], (unsigned long long)(long long)(sqAll[row] * SCALE_S2));
            atomicAdd(&cb[c], 1);
        }
        __syncthreads();
        if (tid < NCLS) {
            s2fixPart[blockIdx.x * 128 + tid] = (long long)s2b[tid];
            cntPart[blockIdx.x * 128 + tid]  = cb[tid];
        }
    } else if (blockIdx.x < S2_BLKS + MSQ_BLKS) {
        // ---------------- msq: sum_c |M_c|^2 partials ----------------
        double* red = reinterpret_cast<double*>(smem);
        const int bid = blockIdx.x - S2_BLKS;    // 0..255
        double local = 0.0;
        const int idx = bid * 200 + tid;
        if (tid < 200 && idx < NBINS) {
            long long ws = 0;
            #pragma unroll 8
            for (int ch = 0; ch < NCHUNK; ++ch)
                ws += (long long)partials[(size_t)ch * NBINS + idx];
            const double m = (double)ws * (1.0 / (double)SCALE_M);
            local = m * m;
        }
        red[tid] = local;
        __syncthreads();
        #pragma unroll
        for (int st = 128; st > 0; st >>= 1) {
            if (tid < st) red[tid] += red[tid + st];
            __syncthreads();
        }
        if (tid == 0) msqPart[bid] = red[0];
    } else {
        // ------------- hinge screen, 128x128 tile, K=32 bf16 MFMA -------------
        auto As = reinterpret_cast<unsigned short (*)[40]>(smem);            // 10.24 KB
        auto Bs = reinterpret_cast<unsigned short (*)[40]>(smem + 10240);    // 10.24 KB
        float* wsum = reinterpret_cast<float*>(smem + 20480);

        const int unit = blockIdx.x - (S2_BLKS + MSQ_BLKS);   // 0..2079
        int rem = unit, br = 0;
        while (rem >= NBLKF - br) { rem -= NBLKF - br; ++br; }
        const int bc = br + rem;

        const int lane = tid & 63;
        const int wid  = tid >> 6;
        const int wr   = wid >> 1;     // 0..1 (64-row slab)
        const int wc   = wid & 1;      // 0..1 (64-col slab)

        // stage both 128x32 bf16 tiles (8KB each): 512 slots of 16B, 2/thread
        #pragma unroll
        for (int it = 0; it < 2; ++it) {
            const int s   = tid + it * 256;
            const int row = s >> 2, q = s & 3;
            short8v va = *reinterpret_cast<const short8v*>(fb32 + (size_t)(br * 128 + row) * KF + q * 8);
            short8v vb = *reinterpret_cast<const short8v*>(fb32 + (size_t)(bc * 128 + row) * KF + q * 8);
            *reinterpret_cast<short8v*>(&As[row][q * 8]) = va;
            *reinterpret_cast<short8v*>(&Bs[row][q * 8]) = vb;
        }
        __syncthreads();

        const f32x4 zero = {0.f, 0.f, 0.f, 0.f};
        short8v a[4], b[4];
        #pragma unroll
        for (int mf = 0; mf < 4; ++mf) {
            const int row = wr * 64 + mf * 16 + (lane & 15);
            a[mf] = *reinterpret_cast<const short8v*>(&As[row][(lane >> 4) * 8]);
        }
        #pragma unroll
        for (int nf = 0; nf < 4; ++nf) {
            const int row = wc * 64 + nf * 16 + (lane & 15);
            b[nf] = *reinterpret_cast<const short8v*>(&Bs[row][(lane >> 4) * 8]);
        }
        f32x4 acc[4][4];
        #pragma unroll
        for (int mf = 0; mf < 4; ++mf)
            #pragma unroll
            for (int nf = 0; nf < 4; ++nf)
                acc[mf][nf] = __builtin_amdgcn_mfma_f32_16x16x32_bf16(a[mf], b[nf], zero, 0, 0, 0);

        const int gi0 = br * 128 + wr * 64;
        const int gj0 = bc * 128 + wc * 64;

        float s32i[16]; int ti[16];
        #pragma unroll
        for (int mf = 0; mf < 4; ++mf)
            #pragma unroll
            for (int j = 0; j < 4; ++j) {
                const int r = gi0 + mf * 16 + (lane >> 4) * 4 + j;
                s32i[mf * 4 + j] = sq32[r];
                ti[mf * 4 + j]   = tgt[r];
            }
        float s32j[4]; int tj[4];
        #pragma unroll
        for (int nf = 0; nf < 4; ++nf) {
            const int c = gj0 + nf * 16 + (lane & 15);
            s32j[nf] = sq32[c];
            tj[nf]   = tgt[c];
        }

        // hot loop: branchless, 64-bit hit mask (64 cells/thread)
        unsigned long long hit = 0ULL;
        #pragma unroll
        for (int mf = 0; mf < 4; ++mf)
            #pragma unroll
            for (int nf = 0; nf < 4; ++nf)
                #pragma unroll
                for (int j = 0; j < 4; ++j) {
                    const int r = gi0 + mf * 16 + (lane >> 4) * 4 + j;
                    const int c = gj0 + nf * 16 + (lane & 15);
                    const float d32 = s32i[mf * 4 + j] + s32j[nf] - 2.0f * acc[mf][nf][j];
                    const bool take = (r != c) & (ti[mf * 4 + j] != tj[nf]) & (d32 < FILT_THR);
                    const int cell = mf * 16 + nf * 4 + j;   // compile-time
                    hit |= take ? (1ULL << cell) : 0ULL;
                }

        // cold path: execz-skipped when no lane has a hit
        float neg = 0.0f;
        if (hit) {
            unsigned long long m = hit;
            while (m) {
                const int bpos = (int)__builtin_ctzll(m);
                m &= m - 1;
                const int mf = (bpos >> 4) & 3;
                const int nf = (bpos >> 2) & 3;
                const int j  = bpos & 3;
                const int r = gi0 + mf * 16 + (lane >> 4) * 4 + j;
                const int c = gj0 + nf * 16 + (lane & 15);
                const float4* xr = reinterpret_cast<const float4*>(f + (size_t)r * Cc);
                const float4* xc = reinterpret_cast<const float4*>(f + (size_t)c * Cc);
                float dd = 0.0f;
                for (int k = 0; k < Cc / 4; ++k) {
                    float4 aa = xr[k], bb = xc[k];
                    float dx = aa.x - bb.x, dy = aa.y - bb.y;
                    float dz = aa.z - bb.z, dw = aa.w - bb.w;
                    dd += dx * dx + dy * dy + dz * dz + dw * dw;
                }
                const float t = (dd > 0.0f) ? (MRG - sqrtf(dd)) : MRG;
                if (t > 0.0f) neg += t * t;
            }
        }

        #pragma unroll
        for (int off = 32; off > 0; off >>= 1) neg += __shfl_down(neg, off, 64);
        if (lane == 0) wsum[wid] = neg;
        __syncthreads();
        if (tid == 0) {
            const float w = (br == bc) ? 1.0f : 2.0f;
            negPart[unit] = (double)(w * (wsum[0] + wsum[1] + wsum[2] + wsum[3]));
        }
    }
}

// ---------------------------------------------------------------- final combine (tiny)
__global__ __launch_bounds__(256) void finish5_kernel(const long long* __restrict__ s2fixPart,
                                                      const int* __restrict__ cntPart,
                                                      const double* __restrict__ msqPart,
                                                      const double* __restrict__ negPart,
                                                      float* __restrict__ out) {
    __shared__ double red[256];
    const int t = threadIdx.x;
    double pa = 0.0;
    if (t < NCLS) {
        long long s2 = 0; int n = 0;
        #pragma unroll
        for (int b = 0; b < S2_BLKS; ++b) {       // fixed order, exact int sums
            s2 += s2fixPart[b * 128 + t];
            n  += cntPart[b * 128 + t];
        }
        pa = 2.0 * (double)n * ((double)s2 * (1.0 / (double)SCALE_S2));
    }
    double v = pa - 2.0 * msqPart[t];             // -2 sum |M_c|^2 (256 entries)
    double nsum = 0.0;
    for (int i = t; i < NPAIRSF; i += 256) nsum += negPart[i];
    red[t] = v + nsum;
    __syncthreads();
    #pragma unroll
    for (int st = 128; st > 0; st >>= 1) {
        if (t < st) red[t] += red[t + st];
        __syncthreads();
    }
    if (t == 0) {
        const double T = (double)Nn * (double)(Nn - 1);
        out[0] = (float)(red[0] / (2.0 * T));
    }
}

// ---------------------------------------------------------------- fp32 fallback (round 1)
__global__ __launch_bounds__(256) void sq_kernel(const float* __restrict__ f,
                                                 float* __restrict__ sq) {
    const int wave = threadIdx.x >> 6;
    const int lane = threadIdx.x & 63;
    const int row  = blockIdx.x * 4 + wave;
    const float4* rp = reinterpret_cast<const float4*>(f + (size_t)row * Cc);
    float4 v0 = rp[lane * 2 + 0];
    float4 v1 = rp[lane * 2 + 1];
    float s = v0.x * v0.x + v0.y * v0.y + v0.z * v0.z + v0.w * v0.w +
              v1.x * v1.x + v1.y * v1.y + v1.z * v1.z + v1.w * v1.w;
    #pragma unroll
    for (int off = 32; off > 0; off >>= 1) s += __shfl_down(s, off, 64);
    if (lane == 0) sq[row] = s;
}

__global__ __launch_bounds__(256) void pair_fp32(const float* __restrict__ f,
                                                 const int* __restrict__ tgt,
                                                 const float* __restrict__ sq,
                                                 double* __restrict__ partials) {
    int rem = blockIdx.x, br = 0;
    while (rem >= NBLK1 - br) { rem -= NBLK1 - br; ++br; }
    const int bc = br + rem;

    __shared__ float As[BK1][LSTR];
    __shared__ float Bs[BK1][LSTR];
    __shared__ float red[256];

    const int tid  = threadIdx.x;
    const int tx   = tid & 15;
    const int ty   = tid >> 4;
    const int row0 = ty * 4;
    const int col0 = tx * 4;

    const float* abase = f + (size_t)br * BM1 * Cc;
    const float* bbase = f + (size_t)bc * BM1 * Cc;

    const int r0 = tid >> 3;
    const int kb = (tid & 7) * 4;

    float acc[4][4] = {};

    for (int k0 = 0; k0 < Cc; k0 += BK1) {
        float4 a0 = *reinterpret_cast<const float4*>(abase + (size_t)(r0)      * Cc + k0 + kb);
        float4 a1 = *reinterpret_cast<const float4*>(abase + (size_t)(r0 + 32) * Cc + k0 + kb);
        float4 b0 = *reinterpret_cast<const float4*>(bbase + (size_t)(r0)      * Cc + k0 + kb);
        float4 b1 = *reinterpret_cast<const float4*>(bbase + (size_t)(r0 + 32) * Cc + k0 + kb);
        __syncthreads();
        As[kb + 0][r0]      = a0.x; As[kb + 1][r0]      = a0.y;
        As[kb + 2][r0]      = a0.z; As[kb + 3][r0]      = a0.w;
        As[kb + 0][r0 + 32] = a1.x; As[kb + 1][r0 + 32] = a1.y;
        As[kb + 2][r0 + 32] = a1.z; As[kb + 3][r0 + 32] = a1.w;
        Bs[kb + 0][r0]      = b0.x; Bs[kb + 1][r0]      = b0.y;
        Bs[kb + 2][r0]      = b0.z; Bs[kb + 3][r0]      = b0.w;
        Bs[kb + 0][r0 + 32] = b1.x; Bs[kb + 1][r0 + 32] = b1.y;
        Bs[kb + 2][r0 + 32] = b1.z; Bs[kb + 3][r0 + 32] = b1.w;
        __syncthreads();
        #pragma unroll
        for (int k = 0; k < BK1; ++k) {
            float4 av = *reinterpret_cast<const float4*>(&As[k][row0]);
            float4 bv = *reinterpret_cast<const float4*>(&Bs[k][col0]);
            acc[0][0] = fmaf(av.x, bv.x, acc[0][0]);
            acc[0][1] = fmaf(av.x, bv.y, acc[0][1]);
            acc[0][2] = fmaf(av.x, bv.z, acc[0][2]);
            acc[0][3] = fmaf(av.x, bv.w, acc[0][3]);
            acc[1][0] = fmaf(av.y, bv.x, acc[1][0]);
            acc[1][1] = fmaf(av.y, bv.y, acc[1][1]);
            acc[1][2] = fmaf(av.y, bv.z, acc[1][2]);
            acc[1][3] = fmaf(av.y, bv.w, acc[1][3]);
            acc[2][0] = fmaf(av.z, bv.x, acc[2][0]);
            acc[2][1] = fmaf(av.z, bv.y, acc[2][1]);
            acc[2][2] = fmaf(av.z, bv.z, acc[2][2]);
            acc[2][3] = fmaf(av.z, bv.w, acc[2][3]);
            acc[3][0] = fmaf(av.w, bv.x, acc[3][0]);
            acc[3][1] = fmaf(av.w, bv.y, acc[3][1]);
            acc[3][2] = fmaf(av.w, bv.z, acc[3][2]);
            acc[3][3] = fmaf(av.w, bv.w, acc[3][3]);
        }
    }

    const int gi = br * BM1 + row0;
    const int gj = bc * BM1 + col0;
    float sqi[4], sqj[4];
    int   ti_[4], tj_[4];
    #pragma unroll
    for (int m = 0; m < 4; ++m) { sqi[m] = sq[gi + m]; ti_[m] = tgt[gi + m]; }
    #pragma unroll
    for (int n = 0; n < 4; ++n) { sqj[n] = sq[gj + n]; tj_[n] = tgt[gj + n]; }

    float pos = 0.f, neg = 0.f;
    #pragma unroll
    for (int m = 0; m < 4; ++m)
        #pragma unroll
        for (int n = 0; n < 4; ++n) {
            if (gi + m == gj + n) continue;
            float d = fmaxf(sqi[m] + sqj[n] - 2.0f * acc[m][n], 0.0f);
            if (ti_[m] == tj_[n]) pos += d;
            else if (d < 1.0f) { float t = MRG - sqrtf(d); neg += t * t; }
        }
    const float w = (br == bc) ? 1.0f : 2.0f;
    red[tid] = w * (pos + neg);
    __syncthreads();
    #pragma unroll
    for (int st = 128; st > 0; st >>= 1) {
        if (tid < st) red[tid] += red[tid + st];
        __syncthreads();
    }
    if (tid == 0) partials[blockIdx.x] = (double)red[0];
}

__global__ __launch_bounds__(256) void finish_kernel(const double* __restrict__ partials,
                                                     float* __restrict__ out, int n) {
    __shared__ double red[256];
    double s = 0.0;
    for (int i = threadIdx.x; i < n; i += 256) s += partials[i];
    red[threadIdx.x] = s;
    __syncthreads();
    #pragma unroll
    for (int st = 128; st > 0; st >>= 1) {
        if (threadIdx.x < st) red[threadIdx.x] += red[threadIdx.x + st];
        __syncthreads();
    }
    if (threadIdx.x == 0) {
        const double t = (double)Nn * (double)(Nn - 1);
        out[0] = (float)(red[0] / (2.0 * t));
    }
}

// ---------------------------------------------------------------- launch
extern "C" void kernel_launch(void* const* d_in, const int* in_sizes, int n_in,
                              void* d_out, int out_size, void* d_ws, size_t ws_size,
                              hipStream_t stream) {
    const float* f   = (const float*)d_in[0];
    const int*   tgt = (const int*)d_in[1];
    float*       out = (float*)d_out;

    // workspace layout (16B-aligned)
    const size_t off_fb32  = 0;                                      // 512 KB
    const size_t off_sq32  = off_fb32  + (size_t)Nn * KF * 2;        // 32 KB
    const size_t off_sqAll = off_sq32  + (size_t)Nn * 4;             // 32 KB
    const size_t off_part  = off_sqAll + (size_t)Nn * 4;             // 32*51200*4 = 6.55 MB
    const size_t off_msq   = off_part  + (size_t)NCHUNK * NBINS * 4; // 256*8
    const size_t off_neg   = off_msq   + (size_t)256 * 8;            // 2080*8
    const size_t off_s2p   = off_neg   + (size_t)NPAIRSF * 8;        // 8*128*8
    const size_t off_cnp   = off_s2p   + (size_t)S2_BLKS * 128 * 8;  // 8*128*4
    const size_t needed    = off_cnp   + (size_t)S2_BLKS * 128 * 4;  // ~7.2 MB

    if (ws_size >= needed) {
        unsigned short* fb32 = (unsigned short*)((char*)d_ws + off_fb32);
        float*     sq32      = (float*)    ((char*)d_ws + off_sq32);
        float*     sqAll     = (float*)    ((char*)d_ws + off_sqAll);
        int*       partials  = (int*)      ((char*)d_ws + off_part);
        double*    msqPart   = (double*)   ((char*)d_ws + off_msq);
        double*    negPart   = (double*)   ((char*)d_ws + off_neg);
        long long* s2fixPart = (long long*)((char*)d_ws + off_s2p);
        int*       cntPart   = (int*)      ((char*)d_ws + off_cnp);

        hipLaunchKernelGGL(fused1_kernel,  dim3(CLSUM_BLKS + PREP_BLKS), dim3(256), 0, stream,
                           f, tgt, fb32, sq32, sqAll, partials);
        hipLaunchKernelGGL(fused2e_kernel, dim3(F2_BLKS),                dim3(256), 0, stream,
                           fb32, f, tgt, sq32, sqAll, partials, negPart, msqPart, s2fixPart, cntPart);
        hipLaunchKernelGGL(finish5_kernel, dim3(1),                      dim3(256), 0, stream,
                           s2fixPart, cntPart, msqPart, negPart, out);
    } else {
        float*  sq       = (float*)d_ws;
        double* partials = (double*)((char*)d_ws + (size_t)Nn * sizeof(float));

        hipLaunchKernelGGL(sq_kernel,     dim3(Nn / 4),  dim3(256), 0, stream, f, sq);
        hipLaunchKernelGGL(pair_fp32,     dim3(NPAIRS1), dim3(256), 0, stream, f, tgt, sq, partials);
        hipLaunchKernelGGL(finish_kernel, dim3(1),       dim3(256), 0, stream, partials, out, NPAIRS1);
    }
}